// Round 7
// baseline (157.433 us; speedup 1.0000x reference)
//
#include <hip/hip_runtime.h>
#include <hip/hip_bf16.h>

// Problem constants (B=2, L=2048, D=1024, H=8, pd=128).
#define L_SEQ   2048
#define D_MODEL 1024
#define B_SZ    2
#define LP      (L_SEQ + 192)   // padded sequence length: 96 front + 96 back
#define PADF    96

typedef __attribute__((ext_vector_type(8))) short bf16x8;
typedef __attribute__((ext_vector_type(4))) float f32x4;

// async global->LDS, 16B per lane (global_load_lds_dwordx4)
__device__ __forceinline__ void gll16(const void* g, void* l) {
    __builtin_amdgcn_global_load_lds(
        (const __attribute__((address_space(1))) unsigned int*)(g),
        (__attribute__((address_space(3))) unsigned int*)(l),
        16, 0, 0);
}

__device__ __forceinline__ ushort bf16_hi(float x) {
    __hip_bfloat16 h = __float2bfloat16(x);
    return *reinterpret_cast<ushort*>(&h);
}
__device__ __forceinline__ float bf16_back(ushort u) {
    __hip_bfloat16 h = *reinterpret_cast<__hip_bfloat16*>(&u);
    return __bfloat162float(h);
}

// ---------------------------------------------------------------------------
// prep: one launch does (a) zero vpad pad rows [384 blocks], (b) split values
// [4096 blocks], (c) split w_in [1024], (d) split w_out [1024].
__global__ __launch_bounds__(256) void prep(const float* __restrict__ values,
                                            const float* __restrict__ w_in,
                                            const float* __restrict__ w_out,
                                            ushort* __restrict__ Ph, ushort* __restrict__ Pl,
                                            ushort* __restrict__ Wh, ushort* __restrict__ Wl,
                                            ushort* __restrict__ W2h, ushort* __restrict__ W2l,
                                            float* __restrict__ vpad)
{
    int blk = blockIdx.x;
    if (blk < 384) {                               // zero the 4 pad regions
        const int r  = blk / 96;
        const int rr = blk % 96;
        const int b  = r >> 1;
        const int row0 = (r & 1) ? (LP - 96) : 0;
        size_t off = ((size_t)b * LP + row0 + rr) * D_MODEL + threadIdx.x * 4;
        *(float4*)(vpad + off) = make_float4(0.f, 0.f, 0.f, 0.f);
        return;
    }
    blk -= 384;
    const float* src;
    ushort *oh, *ol;
    if (blk < 4096)      { src = values; oh = Ph;  ol = Pl;  }
    else if (blk < 5120) { src = w_in;   oh = Wh;  ol = Wl;  blk -= 4096; }
    else                 { src = w_out;  oh = W2h; ol = W2l; blk -= 5120; }

    const size_t i = ((size_t)blk * 256 + threadIdx.x) * 4;
    float4 v = *(const float4*)(src + i);
    float f[4] = {v.x, v.y, v.z, v.w};
    ushort hb[4], lb[4];
    #pragma unroll
    for (int j = 0; j < 4; ++j) {
        hb[j] = bf16_hi(f[j]);
        lb[j] = bf16_hi(f[j] - bf16_back(hb[j]));
    }
    *(ushort4*)(oh + i) = make_ushort4(hb[0], hb[1], hb[2], hb[3]);
    *(ushort4*)(ol + i) = make_ushort4(lb[0], lb[1], lb[2], lb[3]);
}

// ---------------------------------------------------------------------------
// gemm_split: C[M,N] = (Ah+Al)*(Bh+Bl)^T via 3 bf16 MFMA products, fp32 acc.
// M=4096, N=K=1024. Tile 128(M)x64(N), BK=32, 256 threads = 4 waves (2m x 2n),
// each wave 64x32 (acc[4][2], 24 MFMA, 12 ds_read_b128 per K-step).
// Grid 512 = 2 blocks/CU (block-level TLP: two independent barrier domains
// per CU overlap LDS-read phase with MFMA phase — m114/m97 mechanism).
// 3-deep LDS pipeline (3 x 24KB = 72KB), counted vmcnt: 6 loads/tile,
// WAITBAR(6) steady state, triple-unrolled for static buffer indices.
// Bank-conflict fix: k-chunk XOR swizzle on global SOURCE + same involution
// on ds_read. DO_PAD=1 remaps output row m -> vpad row.
template<int DO_PAD>
__global__ __launch_bounds__(256, 2) void gemm_split(const ushort* __restrict__ Ah,
                                                     const ushort* __restrict__ Al,
                                                     const ushort* __restrict__ Bh,
                                                     const ushort* __restrict__ Bl,
                                                     float* __restrict__ C)
{
    // [buf][ A(128x32) | Al(128x32) | Bh(64x32) | Bl(64x32) ] ushort
    // plane offsets within buf: Ah 0, Al 4096, Bh 8192, Bl 10240 (ushorts)
    __shared__ __align__(16) ushort lds[3][12288];

    const int tid = threadIdx.x;
    const int w   = tid >> 6;
    const int l   = tid & 63;

    // XCD swizzle: 512 blocks; xcd = blk&7 owns 2 n-panels (B slice 0.5MB,
    // L2-resident); p = blk>>3 walks 32 m-panels x 2 n-panels.
    const int xcd = blockIdx.x & 7;
    const int p   = blockIdx.x >> 3;                 // 0..63
    const int bn  = (xcd * 2 + (p & 1)) * 64;
    const int bm  = (p >> 1) * 128;

    // --- staging: 256 threads x 16B = 4KB per issue; 6 issues per K-tile ---
    // A planes (8KB each): issue 0 -> rows 0..63, issue 1 -> rows 64..127.
    // B planes (4KB each): one issue, rows 0..63.
    const int srow   = tid >> 2;                          // 0..63
    const int schunk = (tid & 3) ^ ((tid >> 3) & 3);      // pre-swizzled source chunk
    const ushort* gAh0 = Ah + (size_t)(bm + srow) * 1024 + schunk * 8;
    const ushort* gAh1 = gAh0 + (size_t)64 * 1024;
    const ushort* gAl0 = Al + (size_t)(bm + srow) * 1024 + schunk * 8;
    const ushort* gAl1 = gAl0 + (size_t)64 * 1024;
    const ushort* gBh  = Bh + (size_t)(bn + srow) * 1024 + schunk * 8;
    const ushort* gBl  = Bl + (size_t)(bn + srow) * 1024 + schunk * 8;
    const int ldst = tid * 8;                             // linear LDS dest (ushort)

    // --- fragment read params ---
    const int fr  = l & 15;                // row within 16x16 fragment
    const int fq  = l >> 4;                // k-chunk 0..3
    const int swz = (fr >> 1) & 3;         // row-XOR for bank spread
    const int rdo = (fq ^ swz) << 3;       // element offset of swizzled chunk
    const int wr  = w >> 1;                // 0..1 -> m offset wr*64
    const int wc  = w & 1;                 // 0..1 -> n offset wc*32

    f32x4 acc[4][2];
    #pragma unroll
    for (int mi = 0; mi < 4; ++mi)
        #pragma unroll
        for (int ni = 0; ni < 2; ++ni) acc[mi][ni] = (f32x4){0.f, 0.f, 0.f, 0.f};

    #define STAGE(buf, kt)                                        \
        do {                                                      \
            const size_t ko_ = (size_t)(kt) * 32;                 \
            gll16(gAh0 + ko_, &lds[(buf)][ldst]);                 \
            gll16(gAh1 + ko_, &lds[(buf)][2048 + ldst]);          \
            gll16(gAl0 + ko_, &lds[(buf)][4096 + ldst]);          \
            gll16(gAl1 + ko_, &lds[(buf)][6144 + ldst]);          \
            gll16(gBh  + ko_, &lds[(buf)][8192 + ldst]);          \
            gll16(gBl  + ko_, &lds[(buf)][10240 + ldst]);         \
        } while (0)

    // WAITBAR(N): wait until <=N of my loads outstanding, then barrier.
    #define WAITBAR(N) asm volatile("s_waitcnt vmcnt(" #N ")\n\ts_barrier" ::: "memory")

    #define COMPUTE(cur)                                                                   \
        do {                                                                               \
            bf16x8 ah[4], al[4];                                                           \
            _Pragma("unroll")                                                              \
            for (int mi = 0; mi < 4; ++mi) {                                               \
                const int row = wr * 64 + mi * 16 + fr;                                    \
                ah[mi] = *(const bf16x8*)&lds[(cur)][row * 32 + rdo];                      \
                al[mi] = *(const bf16x8*)&lds[(cur)][4096 + row * 32 + rdo];               \
            }                                                                              \
            _Pragma("unroll")                                                              \
            for (int ni = 0; ni < 2; ++ni) {                                               \
                const int row = wc * 32 + ni * 16 + fr;                                    \
                bf16x8 bh = *(const bf16x8*)&lds[(cur)][8192 + row * 32 + rdo];            \
                bf16x8 bl = *(const bf16x8*)&lds[(cur)][10240 + row * 32 + rdo];           \
                _Pragma("unroll")                                                          \
                for (int mi = 0; mi < 4; ++mi)                                             \
                    acc[mi][ni] = __builtin_amdgcn_mfma_f32_16x16x32_bf16(ah[mi], bh, acc[mi][ni], 0, 0, 0); \
                _Pragma("unroll")                                                          \
                for (int mi = 0; mi < 4; ++mi)                                             \
                    acc[mi][ni] = __builtin_amdgcn_mfma_f32_16x16x32_bf16(al[mi], bh, acc[mi][ni], 0, 0, 0); \
                _Pragma("unroll")                                                          \
                for (int mi = 0; mi < 4; ++mi)                                             \
                    acc[mi][ni] = __builtin_amdgcn_mfma_f32_16x16x32_bf16(ah[mi], bl, acc[mi][ni], 0, 0, 0); \
            }                                                                              \
        } while (0)

    // 3-deep pipeline over 32 K-tiles. Invariant at each WAITBAR(6): the
    // tile about to be computed is drained; <=1 younger tile in flight.
    // STAGE(kt+2) overwrites tile kt-1's buffer — safe: the barrier just
    // passed proves all waves finished COMPUTE(kt-1).
    STAGE(0, 0);
    STAGE(1, 1);

    for (int kt = 0; kt < 30; kt += 3) {               // kt = 0,3,...,27
        WAITBAR(6); STAGE(2, kt + 2); COMPUTE(0);
        WAITBAR(6); STAGE(0, kt + 3); COMPUTE(1);
        WAITBAR(6); STAGE(1, kt + 4); COMPUTE(2);
    }
    WAITBAR(6); COMPUTE(0);   // kt=30
    WAITBAR(0); COMPUTE(1);   // kt=31

    #undef STAGE
    #undef WAITBAR
    #undef COMPUTE

    // epilogue: C/D layout col=lane&15, row=(lane>>4)*4+reg  [m89/m91]
    #pragma unroll
    for (int mi = 0; mi < 4; ++mi) {
        #pragma unroll
        for (int ni = 0; ni < 2; ++ni) {
            const int col = bn + wc * 32 + ni * 16 + fr;
            #pragma unroll
            for (int j = 0; j < 4; ++j) {
                const int m = bm + wr * 64 + mi * 16 + fq * 4 + j;
                const size_t row = DO_PAD ? ((size_t)(m >> 11) * LP + (m & (L_SEQ - 1)) + PADF)
                                          : (size_t)m;
                C[row * 1024 + col] = acc[mi][ni][j];
            }
        }
    }
}

// ---------------------------------------------------------------------------
// gauss_conv_split: att[b,q,d] = sum_{delta=-71..56} w[h][delta]*vpad[b,q+delta,d]
// (delta=-72 term <= 5e-16, dropped). Block = 64 d-cols x 128 q-rows; stages
// 256 rows x 64 floats (64KB) in LDS once; each thread owns one d-column and
// 32 q-accumulators, sliding a 47-register window per 16-delta chunk.
// Emits bf16 hi/lo planes directly.
__global__ __launch_bounds__(256) void gauss_conv_split(const float* __restrict__ vpad,
                                                        ushort* __restrict__ Oh,
                                                        ushort* __restrict__ Ol)
{
    __shared__ __align__(16) float xs[256 * 64];   // [row][d] 64KB
    __shared__ float wt[128];                      // delta = j - 71

    const int tid = threadIdx.x;
    const int d0  = blockIdx.x * 64;
    const int q0  = blockIdx.y * 128;
    const int b   = blockIdx.z;
    const int h   = blockIdx.x >> 1;               // 64-wide d block => single head

    if (tid < 128) {
        const float sig = (float)(1 << (h & 3));   // std 1,2,4,8 ; offset = -std
        const float t = ((float)(tid - 71) + sig) / sig;
        wt[tid] = (0.39894228040143267794f / sig) * expf(-0.5f * t * t);
    }

    // stage rows [q0-71, q0+184] x [d0, d0+64)
    const float* src = vpad + ((size_t)b * LP + (PADF - 71) + q0) * 1024 + d0;
    #pragma unroll
    for (int p = 0; p < 16; ++p) {
        const int f   = p * 256 + tid;             // float4 index
        const int row = f >> 4;
        const int c4  = (f & 15) * 4;
        gll16(src + (size_t)row * 1024 + c4, &xs[f * 4]);
    }
    __syncthreads();

    const int d     = tid & 63;
    const int qbase = (tid >> 6) * 32;

    float acc[32];
    #pragma unroll
    for (int qq = 0; qq < 32; ++qq) acc[qq] = 0.f;

    #pragma unroll 1
    for (int c = 0; c < 8; ++c) {
        float xw[47];
        const float* xp = &xs[(qbase + c * 16) * 64 + d];
        #pragma unroll
        for (int j = 0; j < 47; ++j) xw[j] = xp[j * 64];
        #pragma unroll
        for (int dd = 0; dd < 16; ++dd) {
            const float wv = wt[c * 16 + dd];      // block-uniform broadcast
            #pragma unroll
            for (int qq = 0; qq < 32; ++qq)
                acc[qq] = fmaf(wv, xw[dd + qq], acc[qq]);
        }
    }

    ushort* oh = Oh + ((size_t)b * L_SEQ + q0 + qbase) * 1024 + d0 + d;
    ushort* ol = Ol + ((size_t)b * L_SEQ + q0 + qbase) * 1024 + d0 + d;
    #pragma unroll
    for (int qq = 0; qq < 32; ++qq) {
        const ushort hv = bf16_hi(acc[qq]);
        oh[(size_t)qq * 1024] = hv;
        ol[(size_t)qq * 1024] = bf16_hi(acc[qq] - bf16_back(hv));
    }
}

// ---------------------------------------------------------------------------
extern "C" void kernel_launch(void* const* d_in, const int* in_sizes, int n_in,
                              void* d_out, int out_size, void* d_ws, size_t ws_size,
                              hipStream_t stream)
{
    const float* values = (const float*)d_in[0];   // [B,L,D]
    const float* w_in   = (const float*)d_in[1];   // [D,D]
    const float* w_out  = (const float*)d_in[2];   // [D,D]
    float* out = (float*)d_out;                    // [B,L,D]

    // workspace layout (43.5 MB total)
    float*  vpad = (float*)d_ws;                                  // [B][LP][D] fp32
    ushort* Ph  = (ushort*)(vpad + (size_t)B_SZ * LP * D_MODEL);  // [4096][1024] bf16 hi
    ushort* Pl  = Ph  + (size_t)4096 * 1024;                      // lo
    ushort* Wh  = Pl  + (size_t)4096 * 1024;                      // w_in hi
    ushort* Wl  = Wh  + (size_t)1024 * 1024;                      // w_in lo
    ushort* W2h = Wl  + (size_t)1024 * 1024;                      // w_out hi
    ushort* W2l = W2h + (size_t)1024 * 1024;                      // w_out lo

    // 1) one prep launch: zero pads + split values/w_in/w_out into hi/lo planes
    prep<<<dim3(384 + 4096 + 1024 + 1024), dim3(256), 0, stream>>>(
        values, w_in, w_out, Ph, Pl, Wh, Wl, W2h, W2l, vpad);

    // 2) v = values @ w_in^T  (into padded fp32 buffer)
    gemm_split<1><<<dim3(512), dim3(256), 0, stream>>>(Ph, Pl, Wh, Wl, vpad);

    // 3) Gaussian conv -> att, emitted as bf16 hi/lo planes (reuses Ph/Pl)
    dim3 cgrid(D_MODEL / 64, L_SEQ / 128, B_SZ);   // 16 x 16 x 2 = 512 blocks
    gauss_conv_split<<<cgrid, dim3(256), 0, stream>>>(vpad, Ph, Pl);

    // 4) out = att @ w_out^T
    gemm_split<0><<<dim3(512), dim3(256), 0, stream>>>(Ph, Pl, W2h, W2l, out);
}